// Round 1
// baseline (1630.255 us; speedup 1.0000x reference)
//
#include <hip/hip_runtime.h>
#include <math.h>

#define D_MODEL 1024
#define NHEADS 16
#define DH 64
#define BATCH 2
#define SEQ 2048
#define M_TOTAL (BATCH * SEQ)   // 4096

// ---------------------------------------------------------------------------
// GEMM: C[M,N] = A[M,K] @ W[K,N] + bias[N], all fp32 row-major.
// BM=BN=64, BK=16, 256 threads, 4x4 micro-tile per thread.
// ---------------------------------------------------------------------------
__global__ __launch_bounds__(256) void gemm_bias_kernel(
    const float* __restrict__ A, const float* __restrict__ W,
    const float* __restrict__ bias, float* __restrict__ C,
    int M, int N, int K) {
  constexpr int BM = 64, BN = 64, BK = 16;
  __shared__ float As[BK][BM];   // A transposed in LDS
  __shared__ float Bs[BK][BN];

  const int tid = threadIdx.x;
  const int m0 = blockIdx.y * BM;
  const int n0 = blockIdx.x * BN;

  const int tx = tid & 15;        // 0..15 -> output col group
  const int ty = tid >> 4;        // 0..15 -> output row group

  // load mapping
  const int a_row = tid >> 2;            // 0..63
  const int a_col4 = (tid & 3) * 4;      // 0,4,8,12
  const int b_row = tid >> 4;            // 0..15
  const int b_col4 = (tid & 15) * 4;     // 0..60

  float acc[4][4];
#pragma unroll
  for (int i = 0; i < 4; ++i)
#pragma unroll
    for (int j = 0; j < 4; ++j) acc[i][j] = 0.0f;

  for (int k0 = 0; k0 < K; k0 += BK) {
    // stage A tile (BM x BK) transposed
    float4 av = *reinterpret_cast<const float4*>(
        &A[(size_t)(m0 + a_row) * K + k0 + a_col4]);
    // stage B tile (BK x BN)
    float4 bv = *reinterpret_cast<const float4*>(
        &W[(size_t)(k0 + b_row) * N + n0 + b_col4]);
    __syncthreads();
    As[a_col4 + 0][a_row] = av.x;
    As[a_col4 + 1][a_row] = av.y;
    As[a_col4 + 2][a_row] = av.z;
    As[a_col4 + 3][a_row] = av.w;
    *reinterpret_cast<float4*>(&Bs[b_row][b_col4]) = bv;
    __syncthreads();

#pragma unroll
    for (int k = 0; k < BK; ++k) {
      float4 a = *reinterpret_cast<const float4*>(&As[k][ty * 4]);
      float4 b = *reinterpret_cast<const float4*>(&Bs[k][tx * 4]);
      const float ar[4] = {a.x, a.y, a.z, a.w};
      const float br[4] = {b.x, b.y, b.z, b.w};
#pragma unroll
      for (int i = 0; i < 4; ++i)
#pragma unroll
        for (int j = 0; j < 4; ++j) acc[i][j] = fmaf(ar[i], br[j], acc[i][j]);
    }
  }

#pragma unroll
  for (int i = 0; i < 4; ++i) {
    const int row = m0 + ty * 4 + i;
#pragma unroll
    for (int j = 0; j < 4; ++j) {
      const int col = n0 + tx * 4 + j;
      C[(size_t)row * N + col] = acc[i][j] + bias[col];
    }
  }
}

// ---------------------------------------------------------------------------
// Flash-style attention. One thread per query row. Block = 256 threads
// covering 256 consecutive query rows of one (b,h). K/V tiles of 32 keys
// staged in LDS (broadcast reads).
// scores = (qh . kh) / 8 ; attn = softmax_j ; attn *= 1/8 (faithful quirk)
// ---------------------------------------------------------------------------
__global__ __launch_bounds__(256) void attn_kernel(
    const float* __restrict__ qh, const float* __restrict__ kh,
    const float* __restrict__ vh, float* __restrict__ oh) {
  constexpr int TK = 32;
  const int bh = blockIdx.y;            // 0..B*H-1
  const int b = bh / NHEADS;
  const int h = bh % NHEADS;
  const int qrow = blockIdx.x * 256 + threadIdx.x;   // 0..SEQ-1

  const float* qp = qh + ((size_t)(b * SEQ + qrow)) * D_MODEL + h * DH;
  float q[DH];
#pragma unroll
  for (int d = 0; d < DH; ++d) q[d] = qp[d] * 0.125f;  // fold 1/sqrt(dk)

  float o[DH];
#pragma unroll
  for (int d = 0; d < DH; ++d) o[d] = 0.0f;
  float m = -3.0e38f, l = 0.0f;

  __shared__ float Kt[TK][DH];
  __shared__ float Vt[TK][DH];

  const int ltid = threadIdx.x;
  const int lj = ltid >> 3;            // 0..31  key within tile
  const int ld = (ltid & 7) * 8;       // 0..56  dim offset (8 floats)

  for (int j0 = 0; j0 < SEQ; j0 += TK) {
    const float* kp = kh + ((size_t)(b * SEQ + j0 + lj)) * D_MODEL + h * DH + ld;
    const float* vp = vh + ((size_t)(b * SEQ + j0 + lj)) * D_MODEL + h * DH + ld;
    float4 k0v = *reinterpret_cast<const float4*>(kp);
    float4 k1v = *reinterpret_cast<const float4*>(kp + 4);
    float4 v0v = *reinterpret_cast<const float4*>(vp);
    float4 v1v = *reinterpret_cast<const float4*>(vp + 4);
    __syncthreads();
    *reinterpret_cast<float4*>(&Kt[lj][ld]) = k0v;
    *reinterpret_cast<float4*>(&Kt[lj][ld + 4]) = k1v;
    *reinterpret_cast<float4*>(&Vt[lj][ld]) = v0v;
    *reinterpret_cast<float4*>(&Vt[lj][ld + 4]) = v1v;
    __syncthreads();

#pragma unroll 4
    for (int j = 0; j < TK; ++j) {
      float s0 = 0.f, s1 = 0.f, s2 = 0.f, s3 = 0.f;
#pragma unroll
      for (int d = 0; d < DH; d += 4) {
        s0 = fmaf(q[d + 0], Kt[j][d + 0], s0);
        s1 = fmaf(q[d + 1], Kt[j][d + 1], s1);
        s2 = fmaf(q[d + 2], Kt[j][d + 2], s2);
        s3 = fmaf(q[d + 3], Kt[j][d + 3], s3);
      }
      const float s = (s0 + s1) + (s2 + s3);
      if (s > m) {
        const float sc = __expf(m - s);
        l *= sc;
#pragma unroll
        for (int d = 0; d < DH; ++d) o[d] *= sc;
        m = s;
      }
      const float p = __expf(s - m);
      l += p;
#pragma unroll
      for (int d = 0; d < DH; ++d) o[d] = fmaf(p, Vt[j][d], o[d]);
    }
  }

  const float inv = 0.125f / l;   // second 1/sqrt(dk) (faithful quirk)
  float* op = oh + ((size_t)(b * SEQ + qrow)) * D_MODEL + h * DH;
#pragma unroll
  for (int d = 0; d < DH; ++d) op[d] = o[d] * inv;
}

// ---------------------------------------------------------------------------
extern "C" void kernel_launch(void* const* d_in, const int* in_sizes, int n_in,
                              void* d_out, int out_size, void* d_ws, size_t ws_size,
                              hipStream_t stream) {
  const float* q  = (const float*)d_in[0];
  const float* k  = (const float*)d_in[1];
  const float* v  = (const float*)d_in[2];
  const float* wq = (const float*)d_in[3];
  const float* bq = (const float*)d_in[4];
  const float* wk = (const float*)d_in[5];
  const float* bk = (const float*)d_in[6];
  const float* wv = (const float*)d_in[7];
  const float* bv = (const float*)d_in[8];
  const float* wo = (const float*)d_in[9];
  const float* bo = (const float*)d_in[10];
  float* out = (float*)d_out;

  const size_t tensor_elems = (size_t)M_TOTAL * D_MODEL;  // 4M floats
  float* qh = (float*)d_ws;
  float* kh = qh + tensor_elems;
  float* vh = kh + tensor_elems;
  float* ao = vh + tensor_elems;

  dim3 gblock(256);
  dim3 ggrid(D_MODEL / 64, M_TOTAL / 64);   // 16 x 64

  gemm_bias_kernel<<<ggrid, gblock, 0, stream>>>(q, wq, bq, qh, M_TOTAL, D_MODEL, D_MODEL);
  gemm_bias_kernel<<<ggrid, gblock, 0, stream>>>(k, wk, bk, kh, M_TOTAL, D_MODEL, D_MODEL);
  gemm_bias_kernel<<<ggrid, gblock, 0, stream>>>(v, wv, bv, vh, M_TOTAL, D_MODEL, D_MODEL);

  dim3 ablock(256);
  dim3 agrid(SEQ / 256, BATCH * NHEADS);    // 8 x 32
  attn_kernel<<<agrid, ablock, 0, stream>>>(qh, kh, vh, ao);

  gemm_bias_kernel<<<ggrid, gblock, 0, stream>>>(ao, wo, bo, out, M_TOTAL, D_MODEL, D_MODEL);
}

// Round 2
// 612.976 us; speedup vs baseline: 2.6596x; 2.6596x over previous
//
#include <hip/hip_runtime.h>
#include <math.h>

#define D_MODEL 1024
#define NHEADS 16
#define DH 64
#define BATCH 2
#define SEQ 2048
#define M_TOTAL (BATCH * SEQ)   // 4096

typedef __attribute__((ext_vector_type(8))) short bf16x8;   // MFMA A/B frag (4 VGPR)
typedef __attribute__((ext_vector_type(4))) float f32x4;    // MFMA C/D frag
typedef __attribute__((ext_vector_type(8))) unsigned short ushort8;
typedef __attribute__((ext_vector_type(4))) unsigned short ushort4v;

static __device__ __forceinline__ unsigned short f2bf(float x) {
  unsigned int u = __float_as_uint(x);
  unsigned int r = (u + 0x7fffu + ((u >> 16) & 1u)) >> 16;   // RNE
  return (unsigned short)r;
}

// ---------------------------------------------------------------------------
// fp32 GEMM (used for the output projection): C = A@W + bias, fp32 out.
// ---------------------------------------------------------------------------
__global__ __launch_bounds__(256) void gemm_bias_kernel(
    const float* __restrict__ A, const float* __restrict__ W,
    const float* __restrict__ bias, float* __restrict__ C,
    int M, int N, int K) {
  constexpr int BM = 64, BN = 64, BK = 16;
  __shared__ float As[BK][BM];
  __shared__ float Bs[BK][BN];
  const int tid = threadIdx.x;
  const int m0 = blockIdx.y * BM, n0 = blockIdx.x * BN;
  const int tx = tid & 15, ty = tid >> 4;
  const int a_row = tid >> 2, a_col4 = (tid & 3) * 4;
  const int b_row = tid >> 4, b_col4 = (tid & 15) * 4;

  float acc[4][4];
#pragma unroll
  for (int i = 0; i < 4; ++i)
#pragma unroll
    for (int j = 0; j < 4; ++j) acc[i][j] = 0.0f;

  for (int k0 = 0; k0 < K; k0 += BK) {
    float4 av = *reinterpret_cast<const float4*>(&A[(size_t)(m0 + a_row) * K + k0 + a_col4]);
    float4 bv = *reinterpret_cast<const float4*>(&W[(size_t)(k0 + b_row) * N + n0 + b_col4]);
    __syncthreads();
    As[a_col4 + 0][a_row] = av.x; As[a_col4 + 1][a_row] = av.y;
    As[a_col4 + 2][a_row] = av.z; As[a_col4 + 3][a_row] = av.w;
    *reinterpret_cast<float4*>(&Bs[b_row][b_col4]) = bv;
    __syncthreads();
#pragma unroll
    for (int k = 0; k < BK; ++k) {
      float4 a = *reinterpret_cast<const float4*>(&As[k][ty * 4]);
      float4 b = *reinterpret_cast<const float4*>(&Bs[k][tx * 4]);
      const float ar[4] = {a.x, a.y, a.z, a.w};
      const float br[4] = {b.x, b.y, b.z, b.w};
#pragma unroll
      for (int i = 0; i < 4; ++i)
#pragma unroll
        for (int j = 0; j < 4; ++j) acc[i][j] = fmaf(ar[i], br[j], acc[i][j]);
    }
  }
#pragma unroll
  for (int i = 0; i < 4; ++i) {
    const int row = m0 + ty * 4 + i;
#pragma unroll
    for (int j = 0; j < 4; ++j) {
      const int col = n0 + tx * 4 + j;
      C[(size_t)row * N + col] = acc[i][j] + bias[col];
    }
  }
}

// ---------------------------------------------------------------------------
// fp32 GEMM, bf16 output (row-major), with output scale. For qh (0.125), kh.
// ---------------------------------------------------------------------------
__global__ __launch_bounds__(256) void gemm_bias_bf16_kernel(
    const float* __restrict__ A, const float* __restrict__ W,
    const float* __restrict__ bias, unsigned short* __restrict__ C,
    int M, int N, int K, float scale) {
  constexpr int BM = 64, BN = 64, BK = 16;
  __shared__ float As[BK][BM];
  __shared__ float Bs[BK][BN];
  const int tid = threadIdx.x;
  const int m0 = blockIdx.y * BM, n0 = blockIdx.x * BN;
  const int tx = tid & 15, ty = tid >> 4;
  const int a_row = tid >> 2, a_col4 = (tid & 3) * 4;
  const int b_row = tid >> 4, b_col4 = (tid & 15) * 4;

  float acc[4][4];
#pragma unroll
  for (int i = 0; i < 4; ++i)
#pragma unroll
    for (int j = 0; j < 4; ++j) acc[i][j] = 0.0f;

  for (int k0 = 0; k0 < K; k0 += BK) {
    float4 av = *reinterpret_cast<const float4*>(&A[(size_t)(m0 + a_row) * K + k0 + a_col4]);
    float4 bv = *reinterpret_cast<const float4*>(&W[(size_t)(k0 + b_row) * N + n0 + b_col4]);
    __syncthreads();
    As[a_col4 + 0][a_row] = av.x; As[a_col4 + 1][a_row] = av.y;
    As[a_col4 + 2][a_row] = av.z; As[a_col4 + 3][a_row] = av.w;
    *reinterpret_cast<float4*>(&Bs[b_row][b_col4]) = bv;
    __syncthreads();
#pragma unroll
    for (int k = 0; k < BK; ++k) {
      float4 a = *reinterpret_cast<const float4*>(&As[k][ty * 4]);
      float4 b = *reinterpret_cast<const float4*>(&Bs[k][tx * 4]);
      const float ar[4] = {a.x, a.y, a.z, a.w};
      const float br[4] = {b.x, b.y, b.z, b.w};
#pragma unroll
      for (int i = 0; i < 4; ++i)
#pragma unroll
        for (int j = 0; j < 4; ++j) acc[i][j] = fmaf(ar[i], br[j], acc[i][j]);
    }
  }
#pragma unroll
  for (int i = 0; i < 4; ++i) {
    const int row = m0 + ty * 4 + i;
    ushort4v ov;
#pragma unroll
    for (int j = 0; j < 4; ++j) ov[j] = f2bf((acc[i][j] + bias[n0 + tx * 4 + j]) * scale);
    *reinterpret_cast<ushort4v*>(&C[(size_t)row * N + n0 + tx * 4]) = ov;
  }
}

// ---------------------------------------------------------------------------
// fp32 GEMM, bf16 TRANSPOSED output: C_T[b][h][dh][s] for V.
// ---------------------------------------------------------------------------
__global__ __launch_bounds__(256) void gemm_bias_bf16T_kernel(
    const float* __restrict__ A, const float* __restrict__ W,
    const float* __restrict__ bias, unsigned short* __restrict__ CT,
    int M, int N, int K) {
  constexpr int BM = 64, BN = 64, BK = 16;
  __shared__ float As[BK][BM];
  __shared__ float Bs[BK][BN];
  const int tid = threadIdx.x;
  const int m0 = blockIdx.y * BM, n0 = blockIdx.x * BN;
  const int tx = tid & 15, ty = tid >> 4;
  const int a_row = tid >> 2, a_col4 = (tid & 3) * 4;
  const int b_row = tid >> 4, b_col4 = (tid & 15) * 4;

  float acc[4][4];
#pragma unroll
  for (int i = 0; i < 4; ++i)
#pragma unroll
    for (int j = 0; j < 4; ++j) acc[i][j] = 0.0f;

  for (int k0 = 0; k0 < K; k0 += BK) {
    float4 av = *reinterpret_cast<const float4*>(&A[(size_t)(m0 + a_row) * K + k0 + a_col4]);
    float4 bv = *reinterpret_cast<const float4*>(&W[(size_t)(k0 + b_row) * N + n0 + b_col4]);
    __syncthreads();
    As[a_col4 + 0][a_row] = av.x; As[a_col4 + 1][a_row] = av.y;
    As[a_col4 + 2][a_row] = av.z; As[a_col4 + 3][a_row] = av.w;
    *reinterpret_cast<float4*>(&Bs[b_row][b_col4]) = bv;
    __syncthreads();
#pragma unroll
    for (int k = 0; k < BK; ++k) {
      float4 a = *reinterpret_cast<const float4*>(&As[k][ty * 4]);
      float4 b = *reinterpret_cast<const float4*>(&Bs[k][tx * 4]);
      const float ar[4] = {a.x, a.y, a.z, a.w};
      const float br[4] = {b.x, b.y, b.z, b.w};
#pragma unroll
      for (int i = 0; i < 4; ++i)
#pragma unroll
        for (int j = 0; j < 4; ++j) acc[i][j] = fmaf(ar[i], br[j], acc[i][j]);
    }
  }
  // transposed write: CT[((b*16+h)*64+dh)*2048 + s], 4 consecutive s per store
  const int h = n0 >> 6;              // n-tile is 64-aligned -> one head per block
  const int b = m0 >> 11;
  const int s_base = (m0 & 2047) + ty * 4;
#pragma unroll
  for (int j = 0; j < 4; ++j) {
    const int dh = (n0 & 63) + tx * 4 + j;
    const float bb = bias[n0 + tx * 4 + j];
    ushort4v ov;
#pragma unroll
    for (int i = 0; i < 4; ++i) ov[i] = f2bf(acc[i][j] + bb);
    *reinterpret_cast<ushort4v*>(
        &CT[((size_t)((b * NHEADS + h) * DH + dh)) * SEQ + s_base]) = ov;
  }
}

// ---------------------------------------------------------------------------
// MFMA flash attention. Block = 256 thr = 4 waves; wave owns 32 q-rows.
// qh,kh bf16 row-major [b][s][h*64+dh]; vhT bf16 [b][h][dh][s]; oh fp32.
// qh pre-scaled by 1/8; epilogue applies second 1/8 (faithful quirk).
// ---------------------------------------------------------------------------
#define QT 128
#define KT 64
__global__ __launch_bounds__(256) void attn_mfma_kernel(
    const unsigned short* __restrict__ qh, const unsigned short* __restrict__ kh,
    const unsigned short* __restrict__ vhT, float* __restrict__ oh) {
  const int bh = blockIdx.y;
  const int b = bh >> 4, h = bh & 15;
  const int q0 = blockIdx.x * QT;
  const int tid = threadIdx.x;
  const int w = tid >> 6;
  const int l = tid & 63;
  const int n = l & 15, g = l >> 4;

  __shared__ unsigned short Ks[KT * DH];        // [key][dh], XOR-swizzled
  __shared__ unsigned short VsT[DH * KT];       // [dh][key], XOR-swizzled
  __shared__ unsigned short Pw[4][32 * KT];     // per-wave P [qrow][key], swizzled

  // Q A-frags: row = q0 + w*32 + i*16 + n ; k(dh) = kc*32 + g*8 + 0..7
  bf16x8 qf[2][2];
#pragma unroll
  for (int i = 0; i < 2; ++i)
#pragma unroll
    for (int kc = 0; kc < 2; ++kc)
      qf[i][kc] = *reinterpret_cast<const bf16x8*>(
          &qh[((size_t)(b * SEQ + q0 + w * 32 + i * 16 + n)) * D_MODEL + h * DH + kc * 32 + g * 8]);

  f32x4 O[2][4];
  float m_r[2][4], l_r[2][4];
#pragma unroll
  for (int i = 0; i < 2; ++i)
#pragma unroll
    for (int df = 0; df < 4; ++df) O[i][df] = (f32x4)(0.0f);
#pragma unroll
  for (int i = 0; i < 2; ++i)
#pragma unroll
    for (int r = 0; r < 4; ++r) { m_r[i][r] = -3.0e38f; l_r[i][r] = 0.0f; }

  // staging mapping: 128 thr -> K (64 rows x 2 halves), 128 thr -> V^T
  const int sel = tid >> 7;
  const int sidx = tid & 127;
  const int srow = sidx >> 1;
  const int shalf = sidx & 1;

  for (int j0 = 0; j0 < SEQ; j0 += KT) {
    // ---- stage K and V^T tiles (reg -> swizzled LDS) ----
    const unsigned short* src =
        (sel == 0)
            ? &kh[((size_t)(b * SEQ + j0 + srow)) * D_MODEL + h * DH + shalf * 32]
            : &vhT[((size_t)((b * NHEADS + h) * DH + srow)) * SEQ + j0 + shalf * 32];
    ushort8 rv[4];
#pragma unroll
    for (int c = 0; c < 4; ++c) rv[c] = *reinterpret_cast<const ushort8*>(&src[c * 8]);
    __syncthreads();
    unsigned short* dst = (sel == 0) ? Ks : VsT;
#pragma unroll
    for (int c = 0; c < 4; ++c) {
      const int idx = (srow * 64 + shalf * 32 + c * 8) ^ ((srow & 7) << 3);
      *reinterpret_cast<ushort8*>(&dst[idx]) = rv[c];
    }
    __syncthreads();

    // ---- S = Q . K^T  (32 q-rows x 64 keys per wave) ----
    bf16x8 kb[4][2];
#pragma unroll
    for (int f = 0; f < 4; ++f)
#pragma unroll
      for (int kc = 0; kc < 2; ++kc) {
        const int idx = ((f * 16 + n) * 64 + kc * 32 + g * 8) ^ ((n & 7) << 3);
        kb[f][kc] = *reinterpret_cast<const bf16x8*>(&Ks[idx]);
      }
    f32x4 S[2][4];
#pragma unroll
    for (int i = 0; i < 2; ++i)
#pragma unroll
      for (int f = 0; f < 4; ++f) {
        f32x4 acc = (f32x4)(0.0f);
        acc = __builtin_amdgcn_mfma_f32_16x16x32_bf16(qf[i][0], kb[f][0], acc, 0, 0, 0);
        acc = __builtin_amdgcn_mfma_f32_16x16x32_bf16(qf[i][1], kb[f][1], acc, 0, 0, 0);
        S[i][f] = acc;
      }

    // ---- online softmax (rows (g*4+rr)+16i, keys across f and 16 lanes) ----
#pragma unroll
    for (int i = 0; i < 2; ++i) {
#pragma unroll
      for (int rr = 0; rr < 4; ++rr) {
        float mx = fmaxf(fmaxf(S[i][0][rr], S[i][1][rr]), fmaxf(S[i][2][rr], S[i][3][rr]));
        mx = fmaxf(mx, __shfl_xor(mx, 1));
        mx = fmaxf(mx, __shfl_xor(mx, 2));
        mx = fmaxf(mx, __shfl_xor(mx, 4));
        mx = fmaxf(mx, __shfl_xor(mx, 8));
        const float mn = fmaxf(m_r[i][rr], mx);
        const float sc = __expf(m_r[i][rr] - mn);
        m_r[i][rr] = mn;
        float p[4], ps = 0.0f;
#pragma unroll
        for (int f = 0; f < 4; ++f) { p[f] = __expf(S[i][f][rr] - mn); ps += p[f]; }
        ps += __shfl_xor(ps, 1);
        ps += __shfl_xor(ps, 2);
        ps += __shfl_xor(ps, 4);
        ps += __shfl_xor(ps, 8);
        l_r[i][rr] = l_r[i][rr] * sc + ps;
#pragma unroll
        for (int df = 0; df < 4; ++df) O[i][df][rr] *= sc;
        const int row = i * 16 + g * 4 + rr;
#pragma unroll
        for (int f = 0; f < 4; ++f)
          Pw[w][(row * 64 + f * 16 + n) ^ ((row & 7) << 3)] = f2bf(p[f]);
      }
    }

    // ---- O += P . V ----
    bf16x8 pa[2][2];
#pragma unroll
    for (int i = 0; i < 2; ++i)
#pragma unroll
      for (int kcc = 0; kcc < 2; ++kcc) {
        const int row = i * 16 + n;
        const int idx = (row * 64 + kcc * 32 + g * 8) ^ ((n & 7) << 3);
        pa[i][kcc] = *reinterpret_cast<const bf16x8*>(&Pw[w][idx]);
      }
    bf16x8 vb[4][2];
#pragma unroll
    for (int df = 0; df < 4; ++df)
#pragma unroll
      for (int kcc = 0; kcc < 2; ++kcc) {
        const int idx = ((df * 16 + n) * 64 + kcc * 32 + g * 8) ^ ((n & 7) << 3);
        vb[df][kcc] = *reinterpret_cast<const bf16x8*>(&VsT[idx]);
      }
#pragma unroll
    for (int i = 0; i < 2; ++i)
#pragma unroll
      for (int df = 0; df < 4; ++df) {
        O[i][df] = __builtin_amdgcn_mfma_f32_16x16x32_bf16(pa[i][0], vb[df][0], O[i][df], 0, 0, 0);
        O[i][df] = __builtin_amdgcn_mfma_f32_16x16x32_bf16(pa[i][1], vb[df][1], O[i][df], 0, 0, 0);
      }
  }

  // ---- epilogue: oh = O / l * 0.125 (second 1/sqrt(dk)) ----
#pragma unroll
  for (int i = 0; i < 2; ++i) {
#pragma unroll
    for (int rr = 0; rr < 4; ++rr) {
      const float inv = 0.125f / l_r[i][rr];
      const int row = q0 + w * 32 + i * 16 + g * 4 + rr;
#pragma unroll
      for (int df = 0; df < 4; ++df) {
        const int col = h * DH + df * 16 + n;
        oh[((size_t)(b * SEQ + row)) * D_MODEL + col] = O[i][df][rr] * inv;
      }
    }
  }
}

// ---------------------------------------------------------------------------
extern "C" void kernel_launch(void* const* d_in, const int* in_sizes, int n_in,
                              void* d_out, int out_size, void* d_ws, size_t ws_size,
                              hipStream_t stream) {
  const float* q  = (const float*)d_in[0];
  const float* k  = (const float*)d_in[1];
  const float* v  = (const float*)d_in[2];
  const float* wq = (const float*)d_in[3];
  const float* bq = (const float*)d_in[4];
  const float* wk = (const float*)d_in[5];
  const float* bk = (const float*)d_in[6];
  const float* wv = (const float*)d_in[7];
  const float* bv = (const float*)d_in[8];
  const float* wo = (const float*)d_in[9];
  const float* bo = (const float*)d_in[10];
  float* out = (float*)d_out;

  const size_t tensor_elems = (size_t)M_TOTAL * D_MODEL;  // 4M
  unsigned short* qh  = (unsigned short*)d_ws;            // 8MB
  unsigned short* kh  = qh + tensor_elems;                // 8MB
  unsigned short* vhT = kh + tensor_elems;                // 8MB
  float* ao = (float*)(vhT + tensor_elems);               // 16MB

  dim3 gblock(256);
  dim3 ggrid(D_MODEL / 64, M_TOTAL / 64);

  gemm_bias_bf16_kernel<<<ggrid, gblock, 0, stream>>>(q, wq, bq, qh, M_TOTAL, D_MODEL, D_MODEL, 0.125f);
  gemm_bias_bf16_kernel<<<ggrid, gblock, 0, stream>>>(k, wk, bk, kh, M_TOTAL, D_MODEL, D_MODEL, 1.0f);
  gemm_bias_bf16T_kernel<<<ggrid, gblock, 0, stream>>>(v, wv, bv, vhT, M_TOTAL, D_MODEL, D_MODEL);

  dim3 ablock(256);
  dim3 agrid(SEQ / QT, BATCH * NHEADS);   // 16 x 32
  attn_mfma_kernel<<<agrid, ablock, 0, stream>>>(qh, kh, vhT, ao);

  gemm_bias_kernel<<<ggrid, gblock, 0, stream>>>(ao, wo, bo, out, M_TOTAL, D_MODEL, D_MODEL);
}

// Round 4
// 209.875 us; speedup vs baseline: 7.7677x; 2.9207x over previous
//
#include <hip/hip_runtime.h>
#include <math.h>

#define D_MODEL 1024
#define NHEADS 16
#define DH 64
#define BATCH 2
#define SEQ 2048
#define M_TOTAL (BATCH * SEQ)   // 4096

typedef __attribute__((ext_vector_type(8))) short bf16x8;   // MFMA A/B frag (4 VGPR)
typedef __attribute__((ext_vector_type(4))) float f32x4;    // MFMA C/D frag
typedef __attribute__((ext_vector_type(8))) unsigned short ushort8;
typedef unsigned short u16;
typedef unsigned int u32;

static __device__ __forceinline__ u16 f2bf(float x) {
  unsigned int u = __float_as_uint(x);
  unsigned int r = (u + 0x7fffu + ((u >> 16) & 1u)) >> 16;   // RNE
  return (u16)r;
}
// packed pair convert (two RNE rounds, shift/or)
static __device__ __forceinline__ u32 pk2bf(float a, float b) {
  return (u32)f2bf(a) | ((u32)f2bf(b) << 16);
}

// ---------------------------------------------------------------------------
// Weight transpose+convert: W[k][n] fp32 -> WT[n][k] bf16. 64x64 tiles.
// ---------------------------------------------------------------------------
__global__ __launch_bounds__(256) void wtrans_kernel(
    const float* __restrict__ w0, const float* __restrict__ w1,
    const float* __restrict__ w2, const float* __restrict__ w3,
    u16* __restrict__ t0, u16* __restrict__ t1,
    u16* __restrict__ t2, u16* __restrict__ t3) {
  __shared__ float tf[64 * 68];   // padded stride 68 floats (16B-aligned rows)
  const int z = blockIdx.z;
  const float* w = (z == 0) ? w0 : (z == 1) ? w1 : (z == 2) ? w2 : w3;
  u16* wt = (z == 0) ? t0 : (z == 1) ? t1 : (z == 2) ? t2 : t3;
  const int n0 = blockIdx.x * 64, k0 = blockIdx.y * 64;
  const int tid = threadIdx.x;
  const int kl = tid >> 4, nq = (tid & 15) * 4;
#pragma unroll
  for (int c = 0; c < 4; ++c) {
    float4 v = *reinterpret_cast<const float4*>(
        &w[(size_t)(k0 + kl + c * 16) * 1024 + n0 + nq]);
    *reinterpret_cast<float4*>(&tf[(kl + c * 16) * 68 + nq]) = v;
  }
  __syncthreads();
  const int n = tid & 63, kq = tid >> 6;   // n lane-varying -> coalesced-ish stores
  u32 pk[8];
#pragma unroll
  for (int p = 0; p < 8; ++p) {
    float a = tf[(kq * 16 + 2 * p) * 68 + n];
    float b = tf[(kq * 16 + 2 * p + 1) * 68 + n];
    pk[p] = pk2bf(a, b);
  }
  u16* dst = &wt[(size_t)(n0 + n) * 1024 + k0 + kq * 16];
  *reinterpret_cast<uint4*>(dst) = make_uint4(pk[0], pk[1], pk[2], pk[3]);
  *reinterpret_cast<uint4*>(dst + 8) = make_uint4(pk[4], pk[5], pk[6], pk[7]);
}

// ---------------------------------------------------------------------------
// MFMA GEMM geometry: BM=128, BN=64, BK=32, 256 thr = 4 waves (2x2).
// LDS rows padded to 40 ushorts (80B) -> balanced banks for ds_read_b128.
// ---------------------------------------------------------------------------
#define BM 128
#define BN 64
#define BK 32
#define LDA 40

// Fused QKV projection GEMM. blockIdx.z selects q/k/v.
// z=0: qh bf16 row-major, scale 0.125; z=1: kh bf16; z=2: vhT [b][h][dh][s].
__global__ __launch_bounds__(256) void qkv_gemm_kernel(
    const float* __restrict__ q, const float* __restrict__ k, const float* __restrict__ v,
    const u16* __restrict__ wqT, const u16* __restrict__ wkT, const u16* __restrict__ wvT,
    const float* __restrict__ bq, const float* __restrict__ bk, const float* __restrict__ bv,
    u16* __restrict__ qh, u16* __restrict__ kh, u16* __restrict__ vhT) {
  __shared__ u16 lds[9216];       // sA 5120 | sB 2560 ; EPI2 bounce reuses all
  u16* sA = lds;                  // [128][40]
  u16* sB = lds + BM * LDA;       // [64][40]

  const int z = blockIdx.z;
  const float* A = (z == 0) ? q : (z == 1) ? k : v;
  const u16* WT = (z == 0) ? wqT : (z == 1) ? wkT : wvT;
  const float* bias = (z == 0) ? bq : (z == 1) ? bk : bv;

  int wg = blockIdx.x + 16 * blockIdx.y;     // 0..511
  wg = (wg & 7) * 64 + (wg >> 3);            // chunked bijective XCD swizzle
  const int m0 = (wg >> 4) * BM;
  const int n0 = (wg & 15) * BN;

  const int tid = threadIdx.x;
  const int wid = tid >> 6, l = tid & 63;
  const int wr = wid >> 1, wc = wid & 1;
  const int n = l & 15, g = l >> 4;

  const int ar = tid >> 1, ah = tid & 1;     // A staging: row 0..127, 16-float half
  const int br = tid >> 2, bq4 = tid & 3;    // B staging: row 0..63, 8-ushort chunk

  const float* Ap = A + (size_t)(m0 + ar) * 1024 + ah * 16;
  const u16* Bp = WT + (size_t)(n0 + br) * 1024 + bq4 * 8;
  u16* sAw = &sA[ar * LDA + ah * 16];
  u16* sBw = &sB[br * LDA + bq4 * 8];

  f32x4 acc[4][2];
#pragma unroll
  for (int fm = 0; fm < 4; ++fm)
#pragma unroll
    for (int fn = 0; fn < 2; ++fn) acc[fm][fn] = (f32x4)(0.0f);

  for (int k0i = 0; k0i < 1024; k0i += BK) {
    float4 a0 = *reinterpret_cast<const float4*>(Ap + k0i);
    float4 a1 = *reinterpret_cast<const float4*>(Ap + k0i + 4);
    float4 a2 = *reinterpret_cast<const float4*>(Ap + k0i + 8);
    float4 a3 = *reinterpret_cast<const float4*>(Ap + k0i + 12);
    uint4 bv4 = *reinterpret_cast<const uint4*>(Bp + k0i);
    __syncthreads();
    uint4 ua = make_uint4(pk2bf(a0.x, a0.y), pk2bf(a0.z, a0.w),
                          pk2bf(a1.x, a1.y), pk2bf(a1.z, a1.w));
    uint4 ub = make_uint4(pk2bf(a2.x, a2.y), pk2bf(a2.z, a2.w),
                          pk2bf(a3.x, a3.y), pk2bf(a3.z, a3.w));
    *reinterpret_cast<uint4*>(sAw) = ua;
    *reinterpret_cast<uint4*>(sAw + 8) = ub;
    *reinterpret_cast<uint4*>(sBw) = bv4;
    __syncthreads();
    bf16x8 af[4], bfr[2];
#pragma unroll
    for (int f = 0; f < 4; ++f)
      af[f] = *reinterpret_cast<const bf16x8*>(&sA[(wr * 64 + f * 16 + n) * LDA + g * 8]);
#pragma unroll
    for (int f = 0; f < 2; ++f)
      bfr[f] = *reinterpret_cast<const bf16x8*>(&sB[(wc * 32 + f * 16 + n) * LDA + g * 8]);
#pragma unroll
    for (int fm = 0; fm < 4; ++fm)
#pragma unroll
      for (int fn = 0; fn < 2; ++fn)
        acc[fm][fn] = __builtin_amdgcn_mfma_f32_16x16x32_bf16(af[fm], bfr[fn], acc[fm][fn], 0, 0, 0);
  }

  const float bsv0 = bias[n0 + wc * 32 + n];
  const float bsv1 = bias[n0 + wc * 32 + 16 + n];

  if (z < 2) {
    const float scale = (z == 0) ? 0.125f : 1.0f;
    u16* dst = (z == 0) ? qh : kh;
#pragma unroll
    for (int fm = 0; fm < 4; ++fm)
#pragma unroll
      for (int rr = 0; rr < 4; ++rr) {
        const int row = m0 + wr * 64 + fm * 16 + g * 4 + rr;
        dst[(size_t)row * 1024 + n0 + wc * 32 + n] = f2bf((acc[fm][0][rr] + bsv0) * scale);
        dst[(size_t)row * 1024 + n0 + wc * 32 + 16 + n] = f2bf((acc[fm][1][rr] + bsv1) * scale);
      }
  } else {
    // vhT epilogue: per-wave LDS bounce transpose, then coalesced 16B stores.
    __syncthreads();                    // everyone done with sA/sB frags
    u16* bw = lds + wid * 2304;         // 32 dh rows, stride 72 ushorts (144B)
#pragma unroll
    for (int fm = 0; fm < 4; ++fm)
#pragma unroll
      for (int fn = 0; fn < 2; ++fn)
#pragma unroll
        for (int rr = 0; rr < 4; ++rr)
          bw[(fn * 16 + n) * 72 + fm * 16 + g * 4 + rr] =
              f2bf(acc[fm][fn][rr] + (fn ? bsv1 : bsv0));
    const int dh = l >> 1, sp = l & 1;
    const int b = m0 >> 11;
    const int s0 = (m0 & 2047) + wr * 64 + sp * 32;
    const int h = n0 >> 6;
    const int dh_g = wc * 32 + dh;
    u16* gdst = vhT + ((size_t)((b * NHEADS + h) * DH + dh_g)) * SEQ + s0;
#pragma unroll
    for (int c = 0; c < 4; ++c)
      *reinterpret_cast<uint4*>(gdst + c * 8) =
          *reinterpret_cast<const uint4*>(&bw[dh * 72 + sp * 32 + c * 8]);
  }
}

// Output projection GEMM: A bf16 (aob), fp32 output.
__global__ __launch_bounds__(256) void out_gemm_kernel(
    const u16* __restrict__ aob, const u16* __restrict__ woT,
    const float* __restrict__ bo, float* __restrict__ out) {
  __shared__ u16 lds[7680];
  u16* sA = lds;
  u16* sB = lds + BM * LDA;

  int wg = blockIdx.x + 16 * blockIdx.y;
  wg = (wg & 7) * 64 + (wg >> 3);
  const int m0 = (wg >> 4) * BM;
  const int n0 = (wg & 15) * BN;

  const int tid = threadIdx.x;
  const int wid = tid >> 6, l = tid & 63;
  const int wr = wid >> 1, wc = wid & 1;
  const int n = l & 15, g = l >> 4;

  const int ar = tid >> 1, ah = tid & 1;
  const int br = tid >> 2, bq4 = tid & 3;

  const u16* Ap = aob + (size_t)(m0 + ar) * 1024 + ah * 16;
  const u16* Bp = woT + (size_t)(n0 + br) * 1024 + bq4 * 8;
  u16* sAw = &sA[ar * LDA + ah * 16];
  u16* sBw = &sB[br * LDA + bq4 * 8];

  f32x4 acc[4][2];
#pragma unroll
  for (int fm = 0; fm < 4; ++fm)
#pragma unroll
    for (int fn = 0; fn < 2; ++fn) acc[fm][fn] = (f32x4)(0.0f);

  for (int k0i = 0; k0i < 1024; k0i += BK) {
    uint4 la0 = *reinterpret_cast<const uint4*>(Ap + k0i);
    uint4 la1 = *reinterpret_cast<const uint4*>(Ap + k0i + 8);
    uint4 bv4 = *reinterpret_cast<const uint4*>(Bp + k0i);
    __syncthreads();
    *reinterpret_cast<uint4*>(sAw) = la0;
    *reinterpret_cast<uint4*>(sAw + 8) = la1;
    *reinterpret_cast<uint4*>(sBw) = bv4;
    __syncthreads();
    bf16x8 af[4], bfr[2];
#pragma unroll
    for (int f = 0; f < 4; ++f)
      af[f] = *reinterpret_cast<const bf16x8*>(&sA[(wr * 64 + f * 16 + n) * LDA + g * 8]);
#pragma unroll
    for (int f = 0; f < 2; ++f)
      bfr[f] = *reinterpret_cast<const bf16x8*>(&sB[(wc * 32 + f * 16 + n) * LDA + g * 8]);
#pragma unroll
    for (int fm = 0; fm < 4; ++fm)
#pragma unroll
      for (int fn = 0; fn < 2; ++fn)
        acc[fm][fn] = __builtin_amdgcn_mfma_f32_16x16x32_bf16(af[fm], bfr[fn], acc[fm][fn], 0, 0, 0);
  }

  const float bsv0 = bo[n0 + wc * 32 + n];
  const float bsv1 = bo[n0 + wc * 32 + 16 + n];
#pragma unroll
  for (int fm = 0; fm < 4; ++fm)
#pragma unroll
    for (int rr = 0; rr < 4; ++rr) {
      const int row = m0 + wr * 64 + fm * 16 + g * 4 + rr;
      out[(size_t)row * 1024 + n0 + wc * 32 + n] = acc[fm][0][rr] + bsv0;
      out[(size_t)row * 1024 + n0 + wc * 32 + 16 + n] = acc[fm][1][rr] + bsv1;
    }
}

// ---------------------------------------------------------------------------
// MFMA flash attention (bf16 output).
// ---------------------------------------------------------------------------
#define QT 128
#define KT 64
__global__ __launch_bounds__(256) void attn_mfma_kernel(
    const u16* __restrict__ qh, const u16* __restrict__ kh,
    const u16* __restrict__ vhT, u16* __restrict__ aob) {
  const int bh = blockIdx.y;
  const int b = bh >> 4, h = bh & 15;
  const int q0 = blockIdx.x * QT;
  const int tid = threadIdx.x;
  const int w = tid >> 6;
  const int l = tid & 63;
  const int n = l & 15, g = l >> 4;

  __shared__ u16 Ks[KT * DH];
  __shared__ u16 VsT[DH * KT];
  __shared__ u16 Pw[4][32 * KT];

  bf16x8 qf[2][2];
#pragma unroll
  for (int i = 0; i < 2; ++i)
#pragma unroll
    for (int kc = 0; kc < 2; ++kc)
      qf[i][kc] = *reinterpret_cast<const bf16x8*>(
          &qh[((size_t)(b * SEQ + q0 + w * 32 + i * 16 + n)) * D_MODEL + h * DH + kc * 32 + g * 8]);

  f32x4 O[2][4];
  float m_r[2][4], l_r[2][4];
#pragma unroll
  for (int i = 0; i < 2; ++i)
#pragma unroll
    for (int df = 0; df < 4; ++df) O[i][df] = (f32x4)(0.0f);
#pragma unroll
  for (int i = 0; i < 2; ++i)
#pragma unroll
    for (int r = 0; r < 4; ++r) { m_r[i][r] = -3.0e38f; l_r[i][r] = 0.0f; }

  const int sel = tid >> 7;
  const int sidx = tid & 127;
  const int srow = sidx >> 1;
  const int shalf = sidx & 1;

  for (int j0 = 0; j0 < SEQ; j0 += KT) {
    const u16* src =
        (sel == 0)
            ? &kh[((size_t)(b * SEQ + j0 + srow)) * D_MODEL + h * DH + shalf * 32]
            : &vhT[((size_t)((b * NHEADS + h) * DH + srow)) * SEQ + j0 + shalf * 32];
    ushort8 rv[4];
#pragma unroll
    for (int c = 0; c < 4; ++c) rv[c] = *reinterpret_cast<const ushort8*>(&src[c * 8]);
    __syncthreads();
    u16* dst = (sel == 0) ? Ks : VsT;
#pragma unroll
    for (int c = 0; c < 4; ++c) {
      const int idx = (srow * 64 + shalf * 32 + c * 8) ^ ((srow & 7) << 3);
      *reinterpret_cast<ushort8*>(&dst[idx]) = rv[c];
    }
    __syncthreads();

    bf16x8 kb[4][2];
#pragma unroll
    for (int f = 0; f < 4; ++f)
#pragma unroll
      for (int kc = 0; kc < 2; ++kc) {
        const int idx = ((f * 16 + n) * 64 + kc * 32 + g * 8) ^ ((n & 7) << 3);
        kb[f][kc] = *reinterpret_cast<const bf16x8*>(&Ks[idx]);
      }
    f32x4 S[2][4];
#pragma unroll
    for (int i = 0; i < 2; ++i)
#pragma unroll
      for (int f = 0; f < 4; ++f) {
        f32x4 acc = (f32x4)(0.0f);
        acc = __builtin_amdgcn_mfma_f32_16x16x32_bf16(qf[i][0], kb[f][0], acc, 0, 0, 0);
        acc = __builtin_amdgcn_mfma_f32_16x16x32_bf16(qf[i][1], kb[f][1], acc, 0, 0, 0);
        S[i][f] = acc;
      }

#pragma unroll
    for (int i = 0; i < 2; ++i) {
#pragma unroll
      for (int rr = 0; rr < 4; ++rr) {
        float mx = fmaxf(fmaxf(S[i][0][rr], S[i][1][rr]), fmaxf(S[i][2][rr], S[i][3][rr]));
        mx = fmaxf(mx, __shfl_xor(mx, 1));
        mx = fmaxf(mx, __shfl_xor(mx, 2));
        mx = fmaxf(mx, __shfl_xor(mx, 4));
        mx = fmaxf(mx, __shfl_xor(mx, 8));
        const float mn = fmaxf(m_r[i][rr], mx);
        const float sc = __expf(m_r[i][rr] - mn);
        m_r[i][rr] = mn;
        float p[4], ps = 0.0f;
#pragma unroll
        for (int f = 0; f < 4; ++f) { p[f] = __expf(S[i][f][rr] - mn); ps += p[f]; }
        ps += __shfl_xor(ps, 1);
        ps += __shfl_xor(ps, 2);
        ps += __shfl_xor(ps, 4);
        ps += __shfl_xor(ps, 8);
        l_r[i][rr] = l_r[i][rr] * sc + ps;
#pragma unroll
        for (int df = 0; df < 4; ++df) O[i][df][rr] *= sc;
        const int row = i * 16 + g * 4 + rr;
#pragma unroll
        for (int f = 0; f < 4; ++f)
          Pw[w][(row * 64 + f * 16 + n) ^ ((row & 7) << 3)] = f2bf(p[f]);
      }
    }

    bf16x8 pa[2][2];
#pragma unroll
    for (int i = 0; i < 2; ++i)
#pragma unroll
      for (int kcc = 0; kcc < 2; ++kcc) {
        const int row = i * 16 + n;
        const int idx = (row * 64 + kcc * 32 + g * 8) ^ ((n & 7) << 3);
        pa[i][kcc] = *reinterpret_cast<const bf16x8*>(&Pw[w][idx]);
      }
    bf16x8 vb[4][2];
#pragma unroll
    for (int df = 0; df < 4; ++df)
#pragma unroll
      for (int kcc = 0; kcc < 2; ++kcc) {
        const int idx = ((df * 16 + n) * 64 + kcc * 32 + g * 8) ^ ((n & 7) << 3);
        vb[df][kcc] = *reinterpret_cast<const bf16x8*>(&VsT[idx]);
      }
#pragma unroll
    for (int i = 0; i < 2; ++i)
#pragma unroll
      for (int df = 0; df < 4; ++df) {
        O[i][df] = __builtin_amdgcn_mfma_f32_16x16x32_bf16(pa[i][0], vb[df][0], O[i][df], 0, 0, 0);
        O[i][df] = __builtin_amdgcn_mfma_f32_16x16x32_bf16(pa[i][1], vb[df][1], O[i][df], 0, 0, 0);
      }
  }

#pragma unroll
  for (int i = 0; i < 2; ++i) {
#pragma unroll
    for (int rr = 0; rr < 4; ++rr) {
      const float inv = 0.125f / l_r[i][rr];
      const int row = q0 + w * 32 + i * 16 + g * 4 + rr;
#pragma unroll
      for (int df = 0; df < 4; ++df) {
        const int col = h * DH + df * 16 + n;
        aob[((size_t)(b * SEQ + row)) * D_MODEL + col] = f2bf(O[i][df][rr] * inv);
      }
    }
  }
}

// ---------------------------------------------------------------------------
extern "C" void kernel_launch(void* const* d_in, const int* in_sizes, int n_in,
                              void* d_out, int out_size, void* d_ws, size_t ws_size,
                              hipStream_t stream) {
  const float* q  = (const float*)d_in[0];
  const float* k  = (const float*)d_in[1];
  const float* v  = (const float*)d_in[2];
  const float* wq = (const float*)d_in[3];
  const float* bq = (const float*)d_in[4];
  const float* wk = (const float*)d_in[5];
  const float* bk = (const float*)d_in[6];
  const float* wv = (const float*)d_in[7];
  const float* bv = (const float*)d_in[8];
  const float* wo = (const float*)d_in[9];
  const float* bo = (const float*)d_in[10];
  float* out = (float*)d_out;

  const size_t wcount = (size_t)D_MODEL * D_MODEL;        // 1M
  const size_t tcount = (size_t)M_TOTAL * D_MODEL;        // 4M
  u16* wqT = (u16*)d_ws;
  u16* wkT = wqT + wcount;
  u16* wvT = wkT + wcount;
  u16* woT = wvT + wcount;
  u16* qh  = woT + wcount;
  u16* kh  = qh + tcount;
  u16* vhT = kh + tcount;
  u16* aob = vhT + tcount;                                // total 40MB

  dim3 blk(256);

  wtrans_kernel<<<dim3(16, 16, 4), blk, 0, stream>>>(wq, wk, wv, wo, wqT, wkT, wvT, woT);

  qkv_gemm_kernel<<<dim3(16, 32, 3), blk, 0, stream>>>(
      q, k, v, wqT, wkT, wvT, bq, bk, bv, qh, kh, vhT);

  attn_mfma_kernel<<<dim3(SEQ / QT, BATCH * NHEADS), blk, 0, stream>>>(qh, kh, vhT, aob);

  out_gemm_kernel<<<dim3(16, 32), blk, 0, stream>>>(aob, woT, bo, out);
}